// Round 1
// baseline (2404.323 us; speedup 1.0000x reference)
//
#include <hip/hip_runtime.h>

#define EDIM   16
#define HIDDEN 64
#define MDIM   16
#define NDIM   16
#define ADIM   (MDIM * NDIM)   // 256

// One thread per edge (grid-stride). Weights in LDS:
//   sW1t [64][16]  = W1 transposed (hid-major, contiguous 16 floats per k)
//   sW2  [64][256] = W2 rows contiguous
// Per edge: loop k=0..63, recompute hid[k] (16 FMA), then unrolled 16x16
// FMA block macc[m] += hid_k * (W2[k,m*16+n] * h[n]). All LDS reads are
// wave-uniform broadcasts (every lane reads the same W-row address).
__global__ __launch_bounds__(512, 4) void msg_kernel(
    const int*   __restrict__ idx,
    const float* __restrict__ h_w,
    const float* __restrict__ e_vw,
    const float* __restrict__ W1,   // [16][64]
    const float* __restrict__ b1,   // [64]
    const float* __restrict__ W2,   // [64][256]
    const float* __restrict__ b2,   // [256]
    float*       __restrict__ out,  // [n_node][16], pre-zeroed
    int n_edge)
{
    __shared__ float sW1t[HIDDEN * EDIM];   // 4 KB, transposed
    __shared__ float sB1[HIDDEN];
    __shared__ float sW2[HIDDEN * ADIM];    // 64 KB
    __shared__ float sB2[ADIM];

    for (int j = threadIdx.x; j < EDIM * HIDDEN; j += blockDim.x) {
        int i = j >> 6;          // input dim
        int k = j & 63;          // hidden dim
        sW1t[k * EDIM + i] = W1[j];
    }
    for (int j = threadIdx.x; j < HIDDEN; j += blockDim.x) sB1[j] = b1[j];
    for (int j = threadIdx.x; j < HIDDEN * ADIM; j += blockDim.x) sW2[j] = W2[j];
    for (int j = threadIdx.x; j < ADIM; j += blockDim.x) sB2[j] = b2[j];
    __syncthreads();

    const int tid = blockIdx.x * blockDim.x + threadIdx.x;
    const int nthreads = gridDim.x * blockDim.x;

    for (int e = tid; e < n_edge; e += nthreads) {
        // ---- load this edge's e_vw[16] and h_w[16] (float4 x4 each) ----
        float ev[EDIM], h[NDIM];
        const float4* e4 = (const float4*)(e_vw + (size_t)e * EDIM);
        const float4* h4 = (const float4*)(h_w + (size_t)e * NDIM);
        #pragma unroll
        for (int i = 0; i < 4; i++) {
            float4 t = e4[i];
            ev[4*i+0] = t.x; ev[4*i+1] = t.y; ev[4*i+2] = t.z; ev[4*i+3] = t.w;
            float4 u = h4[i];
            h[4*i+0] = u.x; h[4*i+1] = u.y; h[4*i+2] = u.z; h[4*i+3] = u.w;
        }

        // ---- bias term: macc[m] = sum_n b2[m*16+n] * h[n] ----
        float macc[MDIM];
        #pragma unroll
        for (int m = 0; m < MDIM; m++) {
            float a = 0.f;
            #pragma unroll
            for (int n = 0; n < NDIM; n++) a = fmaf(sB2[m * NDIM + n], h[n], a);
            macc[m] = a;
        }

        // ---- main loop over hidden units ----
        for (int k = 0; k < HIDDEN; k++) {
            // hid_k = relu(b1[k] + sum_i ev[i] * W1[i][k])
            float hk = sB1[k];
            const float* w1row = &sW1t[k * EDIM];
            #pragma unroll
            for (int i = 0; i < EDIM; i++) hk = fmaf(ev[i], w1row[i], hk);
            hk = fmaxf(hk, 0.f);

            // macc[m] += hk * sum_n W2[k][m*16+n] * h[n]
            const float* w2row = &sW2[k * ADIM];
            #pragma unroll
            for (int m = 0; m < MDIM; m++) {
                float a = 0.f;
                #pragma unroll
                for (int n = 0; n < NDIM; n++)
                    a = fmaf(w2row[m * NDIM + n], h[n], a);
                macc[m] = fmaf(hk, a, macc[m]);
            }
        }

        // ---- scatter-add to target node ----
        const int node = idx[e];
        float* o = out + (size_t)node * MDIM;
        #pragma unroll
        for (int m = 0; m < MDIM; m++) atomicAdd(o + m, macc[m]);
    }
}

extern "C" void kernel_launch(void* const* d_in, const int* in_sizes, int n_in,
                              void* d_out, int out_size, void* d_ws, size_t ws_size,
                              hipStream_t stream) {
    const int*   idx  = (const int*)  d_in[0];
    const float* h_w  = (const float*)d_in[1];
    const float* e_vw = (const float*)d_in[2];
    // d_in[3] = n_node (scalar on device, unused — out_size covers it)
    const float* W1   = (const float*)d_in[4];
    const float* b1   = (const float*)d_in[5];
    const float* W2   = (const float*)d_in[6];
    const float* b2   = (const float*)d_in[7];
    float* out = (float*)d_out;
    const int n_edge = in_sizes[0];

    // out is re-poisoned to 0xAA before every run — zero it for the atomics.
    hipMemsetAsync(out, 0, (size_t)out_size * sizeof(float), stream);

    // 512 blocks x 512 threads = 2 blocks/CU resident (LDS-capped), grid-stride.
    msg_kernel<<<512, 512, 0, stream>>>(idx, h_w, e_vw, W1, b1, W2, b2, out, n_edge);
}

// Round 2
// 514.482 us; speedup vs baseline: 4.6733x; 4.6733x over previous
//
#include <hip/hip_runtime.h>
#include <stdint.h>

typedef __bf16 bf16x8 __attribute__((ext_vector_type(8)));
typedef float  f32x4  __attribute__((ext_vector_type(4)));

#define EDIM   16
#define HIDDEN 64
#define MDIM   16
#define NDIM   16
// Big GEMM: K' = 66 rows (64 hid + 1 bias(=1.0) + 1 zero) x 16 n = 33 chunks of 32
#define KCHUNKS 33

// truncating f32->bf16 pack of two floats into one dword (x in low half).
// v_perm_b32: sel bytes 6,7 -> src0 bytes 2,3 ; sel 2,3 -> src1 bytes 2,3
__device__ __forceinline__ uint32_t pack_trunc(float x, float y) {
    return __builtin_amdgcn_perm(__builtin_bit_cast(uint32_t, x),
                                 __builtin_bit_cast(uint32_t, y),
                                 0x03020706u);
}

__device__ __forceinline__ uint16_t f32_to_bf16_rne(float f) {
    uint32_t u = __builtin_bit_cast(uint32_t, f);
    u += 0x7FFFu + ((u >> 16) & 1u);
    return (uint16_t)(u >> 16);
}

__device__ __forceinline__ bf16x8 u4_as_bf16x8(uint32_t a, uint32_t b,
                                               uint32_t c, uint32_t d) {
    union { uint32_t u[4]; bf16x8 v; } x;
    x.u[0] = a; x.u[1] = b; x.u[2] = c; x.u[3] = d;
    return x.v;
}

// Per 16-edge tile (one wave):
//   hid-GEMM:  A = [e|1|0..] (16x32, K=32), B = W1ext (32x64) -> hid (16x64), relu
//   big GEMM:  A = U[e][kn] = hid_k*h_n (16x1056), B = W2' (1056x16) -> m (16x16)
// W2' staged in LDS in B-fragment order (one ds_read_b128 per lane per chunk).
// hid round-trips through per-wave LDS (C-layout -> A-layout transform).
__global__ __launch_bounds__(256, 3) void msg_mfma(
    const int*   __restrict__ idx,
    const float* __restrict__ h_w,
    const float* __restrict__ e_vw,
    const float* __restrict__ W1,   // [16][64]
    const float* __restrict__ b1,   // [64]
    const float* __restrict__ W2,   // [64][256]  ([k][m*16+n])
    const float* __restrict__ b2,   // [256]      ([m*16+n])
    float*       __restrict__ out,  // [n_node][16], pre-zeroed
    int n_edge)
{
    // B-fragment-ordered W2ext: sB[c][q][m][j] = W2ext[k=2c+(q>>1)][m*16 + (q&1)*8+j]
    __align__(16) __shared__ ushort sB[KCHUNKS * 512];     // 33792 B
    // per-wave hid transpose: sHid[w][k][e], rows 0..63 = hid, 64 = 1.0, 65 = 0
    __align__(16) __shared__ ushort sHid[4 * 68 * 16];     // 8704 B

    const int tid = threadIdx.x;

    // ---- stage W2ext fragments (once per block) ----
    for (int t = tid; t < KCHUNKS * 512; t += 256) {
        int c = t >> 9, r = t & 511;
        int qq = r >> 7, m = (r >> 3) & 15, j = r & 7;
        int k = 2 * c + (qq >> 1);
        int n = ((qq & 1) << 3) + j;
        float v = 0.f;
        if (k < 64)       v = W2[k * 256 + m * 16 + n];
        else if (k == 64) v = b2[m * 16 + n];
        sB[t] = f32_to_bf16_rne(v);
    }

    const int lane = tid & 63;
    const int q    = lane >> 4;    // quad-row 0..3
    const int col  = lane & 15;
    const int w    = tid >> 6;     // wave in block

    // constant hid rows: k=64 -> 1.0 (bias row), k=65..67 -> 0
    sHid[w * 1088 + (64 + q) * 16 + col] = (q == 0) ? (ushort)0x3F80 : (ushort)0;

    // ---- W1ext B-fragments in registers (once per wave) ----
    // frag[nt] element j = W1ext[k=q*8+j][nt*16+col]; row16 = b1, rows 17..31 = 0
    uint32_t w1u[4][4];
    #pragma unroll
    for (int nt = 0; nt < 4; nt++) {
        #pragma unroll
        for (int d = 0; d < 4; d++) w1u[nt][d] = 0;
        #pragma unroll
        for (int j = 0; j < 8; j++) {
            int k = q * 8 + j;
            float v = 0.f;
            if (k < 16)       v = W1[k * 64 + nt * 16 + col];
            else if (k == 16) v = b1[nt * 16 + col];
            w1u[nt][j >> 1] |= ((uint32_t)f32_to_bf16_rne(v)) << ((j & 1) * 16);
        }
    }
    __syncthreads();

    bf16x8 w1f[4];
    #pragma unroll
    for (int nt = 0; nt < 4; nt++)
        w1f[nt] = u4_as_bf16x8(w1u[nt][0], w1u[nt][1], w1u[nt][2], w1u[nt][3]);

    const int nhalf = (q & 1) << 3;  // which 8 of the 16 dims this quad holds
    const int ntile = (n_edge + 15) >> 4;
    const int wave_id = blockIdx.x * 4 + w;
    const int wstride = gridDim.x * 4;
    if (wave_id >= ntile) return;

    const ushort* hidRd = &sHid[w * 1088 + (q >> 1) * 16 + col]; // + c*32
    ushort*       hidWr = &sHid[w * 1088 + col * 16 + q * 4];    // + nt*256
    const ushort* bRd   = &sB[q * 128 + col * 8];                // + c*512

    // ---- prefetch first tile ----
    int t = wave_id;
    float4 e0, e1, h0, h1; int4 nd;
    {
        int row = min(t * 16 + col, n_edge - 1);
        const float4* ep = (const float4*)(e_vw + (size_t)row * 16 + nhalf);
        e0 = ep[0]; e1 = ep[1];
        const float4* hp = (const float4*)(h_w + (size_t)row * 16 + nhalf);
        h0 = hp[0]; h1 = hp[1];
        int r0 = t * 16 + q * 4;
        nd.x = idx[min(r0 + 0, n_edge - 1)];
        nd.y = idx[min(r0 + 1, n_edge - 1)];
        nd.z = idx[min(r0 + 2, n_edge - 1)];
        nd.w = idx[min(r0 + 3, n_edge - 1)];
    }

    while (true) {
        // ---- issue next tile's loads BEFORE this tile's atomics ----
        int tn = t + wstride;
        bool have_next = (tn < ntile);
        float4 ne0, ne1, nh0, nh1; int4 nnd;
        if (have_next) {
            int row = min(tn * 16 + col, n_edge - 1);
            const float4* ep = (const float4*)(e_vw + (size_t)row * 16 + nhalf);
            ne0 = ep[0]; ne1 = ep[1];
            const float4* hp = (const float4*)(h_w + (size_t)row * 16 + nhalf);
            nh0 = hp[0]; nh1 = hp[1];
            int r0 = tn * 16 + q * 4;
            nnd.x = idx[min(r0 + 0, n_edge - 1)];
            nnd.y = idx[min(r0 + 1, n_edge - 1)];
            nnd.z = idx[min(r0 + 2, n_edge - 1)];
            nnd.w = idx[min(r0 + 3, n_edge - 1)];
        }

        // ---- hid stage: 4 MFMAs, relu, pack, LDS transpose write ----
        uint32_t au0 = pack_trunc(e0.x, e0.y);
        uint32_t au1 = pack_trunc(e0.z, e0.w);
        uint32_t au2 = pack_trunc(e1.x, e1.y);
        uint32_t au3 = pack_trunc(e1.z, e1.w);
        if (q == 2) { au0 = 0x00003F80u; au1 = au2 = au3 = 0; } // bias row k=16 -> 1.0
        else if (q == 3) { au0 = au1 = au2 = au3 = 0; }
        bf16x8 av = u4_as_bf16x8(au0, au1, au2, au3);

        #pragma unroll
        for (int nt = 0; nt < 4; nt++) {
            f32x4 hc = {0.f, 0.f, 0.f, 0.f};
            hc = __builtin_amdgcn_mfma_f32_16x16x32_bf16(av, w1f[nt], hc, 0, 0, 0);
            // C layout: value = hid[e = q*4 + i][n = nt*16 + col]
            uint32_t lo = pack_trunc(fmaxf(hc[0], 0.f), fmaxf(hc[1], 0.f));
            uint32_t hi = pack_trunc(fmaxf(hc[2], 0.f), fmaxf(hc[3], 0.f));
            *(uint2*)(hidWr + nt * 256) = make_uint2(lo, hi);   // sHid[k=nt*16+col][e=q*4..+3]
        }

        // ---- big GEMM: 33 chunks over kn ----
        f32x4 acc = {0.f, 0.f, 0.f, 0.f};
        float hf[8] = {h0.x, h0.y, h0.z, h0.w, h1.x, h1.y, h1.z, h1.w};
        #pragma unroll
        for (int c = 0; c < KCHUNKS; c++) {
            uint16_t hk16 = hidRd[c * 32];                      // hid[k=2c+(q>>1)][e=col]
            float hk = __builtin_bit_cast(float, ((uint32_t)hk16) << 16);
            uint32_t a0 = pack_trunc(hk * hf[0], hk * hf[1]);
            uint32_t a1 = pack_trunc(hk * hf[2], hk * hf[3]);
            uint32_t a2 = pack_trunc(hk * hf[4], hk * hf[5]);
            uint32_t a3 = pack_trunc(hk * hf[6], hk * hf[7]);
            bf16x8 af = u4_as_bf16x8(a0, a1, a2, a3);
            bf16x8 bfb = *(const bf16x8*)(bRd + c * 512);       // ds_read_b128
            acc = __builtin_amdgcn_mfma_f32_16x16x32_bf16(af, bfb, acc, 0, 0, 0);
        }

        // ---- epilogue: C[row=e=q*4+i][col=m] -> atomics ----
        int r0 = t * 16 + q * 4;
        if (r0 + 0 < n_edge) atomicAdd(out + (size_t)nd.x * 16 + col, acc[0]);
        if (r0 + 1 < n_edge) atomicAdd(out + (size_t)nd.y * 16 + col, acc[1]);
        if (r0 + 2 < n_edge) atomicAdd(out + (size_t)nd.z * 16 + col, acc[2]);
        if (r0 + 3 < n_edge) atomicAdd(out + (size_t)nd.w * 16 + col, acc[3]);

        if (!have_next) break;
        t = tn;
        e0 = ne0; e1 = ne1; h0 = nh0; h1 = nh1; nd = nnd;
    }
}

extern "C" void kernel_launch(void* const* d_in, const int* in_sizes, int n_in,
                              void* d_out, int out_size, void* d_ws, size_t ws_size,
                              hipStream_t stream) {
    const int*   idx  = (const int*)  d_in[0];
    const float* h_w  = (const float*)d_in[1];
    const float* e_vw = (const float*)d_in[2];
    const float* W1   = (const float*)d_in[4];
    const float* b1   = (const float*)d_in[5];
    const float* W2   = (const float*)d_in[6];
    const float* b2   = (const float*)d_in[7];
    float* out = (float*)d_out;
    const int n_edge = in_sizes[0];

    hipMemsetAsync(out, 0, (size_t)out_size * sizeof(float), stream);
    msg_mfma<<<2048, 256, 0, stream>>>(idx, h_w, e_vw, W1, b1, W2, b2, out, n_edge);
}